// Round 10
// baseline (375.113 us; speedup 1.0000x reference)
//
#include <hip/hip_runtime.h>
#include <math.h>

#define SEQL 784
#define HIDN 512
#define OUTD 10

typedef float v2 __attribute__((ext_vector_type(2)));

// DPP mov: lanes not selected by row_mask, or with invalid source (bound_ctrl),
// yield 0. Single-use results feeding a TIED VOP2 (v_fmac/v_add) fold into
// v_{add,fmac}_f32_dpp; VOP3 v_fma_f32 cannot take DPP on CDNA, so the scan
// is phrased as two serial fmac-shaped updates per value.
template<int CTRL, int RM>
__device__ __forceinline__ float dpp0(float v) {
    int r = __builtin_amdgcn_update_dpp(0, __builtin_bit_cast(int, v),
                                        CTRL, RM, 0xF, true);
    return __builtin_bit_cast(float, r);
}
__device__ __forceinline__ v2 sp(float v) { v2 r; r.x = v; r.y = v; return r; }
__device__ __forceinline__ v2 vfma(v2 a, v2 b, v2 c) {
    return __builtin_elementwise_fma(a, b, c);   // -> v_pk_fma_f32
}

// M[i][o] = sum_j C1[j][i] * W[j][o]  (512 x 10): logits = h2f @ M + b.
__global__ __launch_bounds__(256) void compute_M(const float* __restrict__ C1,
                                                 const float* __restrict__ W,
                                                 float* __restrict__ M) {
    __shared__ float Ws[HIDN * OUTD];
    __shared__ float red[4][64][OUTD];
    const int lane = threadIdx.x & 63, w = threadIdx.x >> 6;
    const int i = blockIdx.x * 64 + lane;
    for (int idx = threadIdx.x; idx < HIDN * OUTD; idx += 256) Ws[idx] = W[idx];
    __syncthreads();
    float acc[OUTD];
#pragma unroll
    for (int o = 0; o < OUTD; ++o) acc[o] = 0.f;
    for (int j = w * 128; j < w * 128 + 128; ++j) {
        float cv = C1[j * HIDN + i];
#pragma unroll
        for (int o = 0; o < OUTD; ++o) acc[o] = fmaf(cv, Ws[j * OUTD + o], acc[o]);
    }
#pragma unroll
    for (int o = 0; o < OUTD; ++o) red[w][lane][o] = acc[o];
    __syncthreads();
    if (w == 0) {
#pragma unroll
        for (int o = 0; o < OUTD; ++o)
            M[i * OUTD + o] = (red[0][lane][o] + red[1][lane][o]) +
                              (red[2][lane][o] + red[3][lane][o]);
    }
}

// Wave affine scan via DPP; two tied fmacs per value per level (bc-term
// first: consumes OLD s; r updated after s so ac-term sees OLD r).
#define LVL(CTRL, RM, L) {                                                   \
        s.x = fmaf(dpp0<CTRL, RM>(s.x), bc[L], s.x);                         \
        s.x = fmaf(dpp0<CTRL, RM>(r.x), ac[L], s.x);                         \
        s.y = fmaf(dpp0<CTRL, RM>(s.y), bc[L], s.y);                         \
        s.y = fmaf(dpp0<CTRL, RM>(r.y), ac[L], s.y);                         \
        r.x += dpp0<CTRL, RM>(r.x);                                          \
        r.y += dpp0<CTRL, RM>(r.y); }

// Trans/VALU-fused SSM step (iteration k), pair-body form.  Per j-pair
// (j0 = 2jp, j1 = 2jp+1):
//   B(k-1): yy = K*S0 + w8; E = exp2(yy); ep = (E+1)/2 for both j's, then
//           ONE shared rcp: rp4 = rcp(pmA*pmB); 1/pmA = pmB*rp4, etc.
//           (4-way reciprocal sharing: 4 rcp/step instead of 8.)
//   A(k)  : H_j(k-1) = pk_fma(ep, -G2/pm, G2)  (component-swapped tanh pair)
//           part += C0d2*H_layer1; pass1 chains in_, w8(k), sg, rt in exact
//           j order (B reads w8 old values before A overwrites them).
//   r~-fold: FT_j == -1568*mE2_j exactly (rt seeded with -1568*du).
//   sigma-rescale: s = PiL*sg, w8 coeff mE2_j*Pi_{j-1} == K_j.
// Deferred-H: y0cur = part(k-1) set at step k, consumed as du at step k+1
// (exact lag 2 for the layer-2 stream).  Init w8 = 0, S0 = 0 -> H(-1) = 0.
template<int PAR>
static __device__ __forceinline__ void fstep(
        v2 (&w8)[8], v2& S0, float& y0cur, float u,
        const float (&P2)[8], const float (&G2)[8], const float (&mE2)[8],
        const float (&K_)[8], const float (&Psp)[8],
        const float (&C0d2)[8], float PiL,
        const float (&ac)[6], const float (&bc)[6]) {
    v2 du;
    if (PAR) { du.x = y0cur; du.y = u; } else { du.x = u; du.y = y0cur; }
    v2 rt = sp(-1568.0f) * du;
    v2 sg = sp(0.f);
    float part = 0.f;
#pragma unroll
    for (int jp = 0; jp < 4; ++jp) {
        const int j0 = 2 * jp, j1 = 2 * jp + 1;
        // ---- B(k-1) pair: finish previous step's tanh inputs, shared rcp
        v2 yy0 = vfma(sp(K_[j0]), S0, w8[j0]);
        v2 yy1 = vfma(sp(K_[j1]), S0, w8[j1]);
        v2 E0, E1;
        E0.x = __builtin_amdgcn_exp2f(yy0.x);
        E0.y = __builtin_amdgcn_exp2f(yy0.y);
        E1.x = __builtin_amdgcn_exp2f(yy1.x);
        E1.y = __builtin_amdgcn_exp2f(yy1.y);
        v2 ep0 = vfma(E0, sp(0.5f), sp(0.5f));     // (E+1)/2
        v2 ep1 = vfma(E1, sp(0.5f), sp(0.5f));
        float pmA = ep0.x * ep0.y;
        float pmB = ep1.x * ep1.y;
        float rp4 = __builtin_amdgcn_rcpf(pmA * pmB);
        float rpA = pmB * rp4;                     // 1/pmA
        float rpB = pmA * rp4;                     // 1/pmB
        // ---- A(k) body j0: materialize H_j0(k-1), dot-partial, pass 1
        {
            float nt = -G2[j0] * rpA;
            v2 Hj = vfma(ep0, sp(nt), sp(G2[j0]));  // swapped tanh pair * G2
            part = fmaf(C0d2[j0], PAR ? Hj.y : Hj.x, part);
            v2 in_ = vfma(sp(mE2[j0]), rt, Hj);
            w8[j0] = (j0 == 0) ? in_ : vfma(sp(K_[j0]), sg, in_);
            sg = (j0 == 0) ? sp(Psp[0]) * in_ : vfma(sp(Psp[j0]), in_, sg);
            rt = vfma(sp(P2[j0]), Hj, rt);
        }
        // ---- A(k) body j1
        {
            float nt = -G2[j1] * rpB;
            v2 Hj = vfma(ep1, sp(nt), sp(G2[j1]));
            part = fmaf(C0d2[j1], PAR ? Hj.y : Hj.x, part);
            v2 in_ = vfma(sp(mE2[j1]), rt, Hj);
            w8[j1] = vfma(sp(K_[j1]), sg, in_);
            sg = vfma(sp(Psp[j1]), in_, sg);
            rt = vfma(sp(P2[j1]), Hj, rt);
        }
    }
    v2 r = vfma(sp(1568.0f), du, rt);              // recover true r
    v2 s = sp(PiL) * sg;                           // true local s for the scan

    // part-reduce (part = y0(k-1)): independent DPP chain, interleaves with
    // the scan below; consumed only at step k+1's du.
    part += dpp0<0x111, 0xF>(part);
    part += dpp0<0x112, 0xF>(part);
    part += dpp0<0x114, 0xF>(part);
    part += dpp0<0x118, 0xF>(part);
    part += dpp0<0x142, 0xA>(part);
    part += dpp0<0x143, 0xC>(part);

    LVL(0x111, 0xF, 0)   // row_shr:1
    LVL(0x112, 0xF, 1)   // row_shr:2
    LVL(0x114, 0xF, 2)   // row_shr:4
    LVL(0x118, 0xF, 3)   // row_shr:8
    LVL(0x142, 0xA, 4)   // row_bcast:15 -> rows 1,3
    LVL(0x143, 0xC, 5)   // row_bcast:31 -> rows 2,3

    v2 t = r + s;
    S0.x = dpp0<0x138, 0xF>(t.x);                  // exclusive: lane0 = 0
    S0.y = dpp0<0x138, 0xF>(t.y);
    y0cur = __builtin_bit_cast(float,
              __builtin_amdgcn_readlane(__builtin_bit_cast(int, part), 63));
}

// One wave per batch row; lane owns 8 hidden elems; layers 1/2 ride in .x/.y
// of packed fp32 (parity-alternating order), layer 2 lagging TWO steps.
// 98 phases x 8 steps; u's double-buffered (phase p prefetches p+1's pair of
// float4 so the ds_read latency hides under 8 steps of compute).
__global__ __launch_bounds__(256, 1) void ssm_main(const float* __restrict__ x,
                                                   const float* __restrict__ C0,
                                                   const float* __restrict__ Mmat,
                                                   const float* __restrict__ bias,
                                                   float* __restrict__ out) {
    const int tid = threadIdx.x;
    const int wave = tid >> 6;
    const int lane = tid & 63;
    const int row = blockIdx.x * 4 + wave;

    __shared__ __align__(16) float xs[4][SEQL + 8];   // row stride 792 (16B aligned)

    const float DEL = 1.0f / 784.0f;
    {
        const float4* __restrict__ xv =
            (const float4*)(x + (size_t)blockIdx.x * 4 * SEQL);
#pragma unroll
        for (int it = 0; it < 4; ++it) {
            int idx = tid + it * 256;                 // float4 index, need < 784
            if (idx < SEQL) {
                float4 v = xv[idx];
                int r = idx / (SEQL / 4);
                int c = (idx % (SEQL / 4)) * 4;
                float4 w;
                w.x = DEL * v.x; w.y = DEL * v.y;
                w.z = DEL * v.z; w.w = DEL * v.w;
                *(float4*)&xs[r][c] = w;
            }
        }
    }
    if (tid < 32) xs[tid >> 3][SEQL + (tid & 7)] = 0.f;
    __syncthreads();

    // ---- per-lane constants (fp64 -> fp32, matching reference f64 A_d/B_d)
    const double cd = 1.0 / 1568.0;            // step/2
    const double F = 2.0 * 1.4426950408889634; // 2*log2(e) fold for exp2
    float P2[8], G2[8], mE2[8], C0d2[8], K_[8], Psp[8], PiL;
    double apD = 0.0, bpD = 1.0;               // in-lane partial (alpha, beta)
    double Aprod = 1.0;                        // prod of a_m, m < j
#pragma unroll
    for (int j = 0; j < 8; ++j) {
        int i = lane * 8 + j;
        double Pd = sqrt(1.0 + 2.0 * (double)i);
        double dd = 1.0 + cd * (double)(i + 1);
        double fd = 1.0 / dd;
        double ad = (1.0 - cd * (double)i) * fd;
        double mEd = -cd * Pd * fd;
        double ed = Pd * mEd;                   // -cP^2/d ; note 1 - a + e == 0
        double Gd = (1.0 - cd * (double)(i + 1)) * fd;
        double G2d = F * Gd;
        apD = ad * apD + ed;
        bpD = ad * bpD;
        P2[j]  = (float)(Pd / G2d);             // r advances on H = G2*h
        G2[j]  = (float)G2d;
        mE2[j] = (float)(F * mEd);              // FT_j == -1568*mE2_j
        K_[j]  = (float)(F * mEd * Aprod);      // mE2_j * prod_{m<j} a_m
        Psp[j] = (float)((Pd / F) / (Aprod * ad)); // Ps_j / Pi_j
        Aprod *= ad;
        C0d2[j] = (float)((double)DEL * (double)C0[i] / G2d);
    }
    PiL = (float)Aprod;                         // Pi_7
    // ---- scan-level constants mirroring the DPP segment structure
    float ac[6], bc[6];
    {
        double al = apD, be = bpD;
        int rl = lane & 15;
#pragma unroll
        for (int L = 0; L < 4; ++L) {          // row_shr:1,2,4,8 (row-capped)
            int d = 1 << L;
            ac[L] = (float)al; bc[L] = (float)be;
            double pa = __shfl_up(al, d, 64);
            double pb = __shfl_up(be, d, 64);
            if (rl >= d) { al += be * pa; be *= pb; }
        }
        ac[4] = (float)al; bc[4] = (float)be;  // row_bcast:15 -> rows 1,3
        {
            int src = (lane & 32) + 15;
            double pa = __shfl(al, src, 64);
            double pb = __shfl(be, src, 64);
            if (lane & 16) { al += be * pa; be *= pb; }
        }
        ac[5] = (float)al; bc[5] = (float)be;  // row_bcast:31 -> rows 2,3
        {
            double pa = __shfl(al, 31, 64);
            double pb = __shfl(be, 31, 64);
            if (lane >= 32) { al += be * pa; be *= pb; }
        }
    }

    v2 w8[8], S0 = sp(0.f);
#pragma unroll
    for (int j = 0; j < 8; ++j) w8[j] = sp(0.f);
    float y0cur = 0.f;
    const float* xrow = xs[wave];

    float4 cu0 = *(const float4*)&xrow[0];
    float4 cu1 = *(const float4*)&xrow[4];
    for (int p = 0; p < 98; ++p) {
        // prefetch next phase's u pair (p=97 reads the zeroed pad, in-bounds)
        float4 nu0 = *(const float4*)&xrow[(p + 1) * 8];
        float4 nu1 = *(const float4*)&xrow[(p + 1) * 8 + 4];
        float ub[8] = {cu0.x, cu0.y, cu0.z, cu0.w, cu1.x, cu1.y, cu1.z, cu1.w};
#pragma unroll
        for (int q = 0; q < 4; ++q) {
            fstep<0>(w8, S0, y0cur, ub[2 * q],     P2, G2, mE2, K_, Psp,
                     C0d2, PiL, ac, bc);
            fstep<1>(w8, S0, y0cur, ub[2 * q + 1], P2, G2, mE2, K_, Psp,
                     C0d2, PiL, ac, bc);
        }
        cu0 = nu0; cu1 = nu1;
    }
    // pad steps k = 784 (even), 785 (odd): u = 0
    fstep<0>(w8, S0, y0cur, 0.f, P2, G2, mE2, K_, Psp, C0d2, PiL, ac, bc);
    fstep<1>(w8, S0, y0cur, 0.f, P2, G2, mE2, K_, Psp, C0d2, PiL, ac, bc);

    // ---- tail-B: materialize final layer-2 state from (S0, w8) of step 785.
    // A(785) was odd-parity: streams (.x = L2, .y = L1); the swapped tanh
    // pair puts layer-2 = 1 - rp*ep.y (unscaled; G2 cancels in the dot).
    float hv[8];
#pragma unroll
    for (int j = 0; j < 8; ++j) {
        v2 yy = vfma(sp(K_[j]), S0, w8[j]);
        v2 E;
        E.x = __builtin_amdgcn_exp2f(yy.x);
        E.y = __builtin_amdgcn_exp2f(yy.y);
        v2 ep = vfma(E, sp(0.5f), sp(0.5f));
        float rp = __builtin_amdgcn_rcpf(ep.x * ep.y);
        hv[j] = fmaf(-rp, ep.y, 1.0f);         // tanh of the .x (L2) stream
    }

    // ---- epilogue: logits[row] = h2_final @ M + b (M direct from global/L2)
    float acc[OUTD];
#pragma unroll
    for (int o = 0; o < OUTD; ++o) acc[o] = 0.f;
#pragma unroll
    for (int j = 0; j < 8; ++j) {
        int i = lane * 8 + j;
#pragma unroll
        for (int o = 0; o < OUTD; ++o)
            acc[o] = fmaf(hv[j], Mmat[i * OUTD + o], acc[o]);
    }
#pragma unroll
    for (int o = 0; o < OUTD; ++o) {
#pragma unroll
        for (int d = 32; d; d >>= 1) acc[o] += __shfl_xor(acc[o], d, 64);
    }
    if (lane == 0) {
#pragma unroll
        for (int o = 0; o < OUTD; ++o) out[row * OUTD + o] = acc[o] + bias[o];
    }
}

extern "C" void kernel_launch(void* const* d_in, const int* in_sizes, int n_in,
                              void* d_out, int out_size, void* d_ws, size_t ws_size,
                              hipStream_t stream) {
    const float* x  = (const float*)d_in[0];  // (1024, 784)
    const float* C0 = (const float*)d_in[1];  // (1, 512)
    const float* C1 = (const float*)d_in[2];  // (512, 512)
    const float* W  = (const float*)d_in[3];  // (512, 10)
    const float* b  = (const float*)d_in[4];  // (10,)
    float* M = (float*)d_ws;                  // 512*10 fp32 scratch

    compute_M<<<dim3(8), dim3(256), 0, stream>>>(C1, W, M);
    ssm_main<<<dim3(256), dim3(256), 0, stream>>>(x, C0, M, b, (float*)d_out);
}

// Round 11
// 358.234 us; speedup vs baseline: 1.0471x; 1.0471x over previous
//
#include <hip/hip_runtime.h>
#include <math.h>

#define SEQL 784
#define HIDN 512
#define OUTD 10

typedef float v2 __attribute__((ext_vector_type(2)));

// DPP mov: lanes not selected by row_mask, or with invalid source (bound_ctrl),
// yield 0. Single-use results feeding a TIED VOP2 (v_fmac/v_add) fold into
// v_{add,fmac}_f32_dpp; VOP3 v_fma_f32 cannot take DPP on CDNA, so the scan
// is phrased as two serial fmac-shaped updates per value.
template<int CTRL, int RM>
__device__ __forceinline__ float dpp0(float v) {
    int r = __builtin_amdgcn_update_dpp(0, __builtin_bit_cast(int, v),
                                        CTRL, RM, 0xF, true);
    return __builtin_bit_cast(float, r);
}
__device__ __forceinline__ v2 sp(float v) { v2 r; r.x = v; r.y = v; return r; }
__device__ __forceinline__ v2 vfma(v2 a, v2 b, v2 c) {
    return __builtin_elementwise_fma(a, b, c);   // -> v_pk_fma_f32 (full-rate)
}

// M[i][o] = sum_j C1[j][i] * W[j][o]  (512 x 10): logits = h2f @ M + b.
__global__ __launch_bounds__(256) void compute_M(const float* __restrict__ C1,
                                                 const float* __restrict__ W,
                                                 float* __restrict__ M) {
    __shared__ float Ws[HIDN * OUTD];
    __shared__ float red[4][64][OUTD];
    const int lane = threadIdx.x & 63, w = threadIdx.x >> 6;
    const int i = blockIdx.x * 64 + lane;
    for (int idx = threadIdx.x; idx < HIDN * OUTD; idx += 256) Ws[idx] = W[idx];
    __syncthreads();
    float acc[OUTD];
#pragma unroll
    for (int o = 0; o < OUTD; ++o) acc[o] = 0.f;
    for (int j = w * 128; j < w * 128 + 128; ++j) {
        float cv = C1[j * HIDN + i];
#pragma unroll
        for (int o = 0; o < OUTD; ++o) acc[o] = fmaf(cv, Ws[j * OUTD + o], acc[o]);
    }
#pragma unroll
    for (int o = 0; o < OUTD; ++o) red[w][lane][o] = acc[o];
    __syncthreads();
    if (w == 0) {
#pragma unroll
        for (int o = 0; o < OUTD; ++o)
            M[i * OUTD + o] = (red[0][lane][o] + red[1][lane][o]) +
                              (red[2][lane][o] + red[3][lane][o]);
    }
}

// Wave affine scan via DPP; two tied fmacs per value per level (bc-term
// first: consumes OLD s; r updated after s so ac-term sees OLD r).
#define LVL(CTRL, RM, L) {                                                   \
        s.x = fmaf(dpp0<CTRL, RM>(s.x), bc[L], s.x);                         \
        s.x = fmaf(dpp0<CTRL, RM>(r.x), ac[L], s.x);                         \
        s.y = fmaf(dpp0<CTRL, RM>(s.y), bc[L], s.y);                         \
        s.y = fmaf(dpp0<CTRL, RM>(r.y), ac[L], s.y);                         \
        r.x += dpp0<CTRL, RM>(r.x);                                          \
        r.y += dpp0<CTRL, RM>(r.y); }

// Trans/VALU-fused SSM step (iteration k).  The j-loop interleaves, per j:
//   B(k-1): yy_j = K_j*S0 + w8_j; E = exp2(yy); ep = (E+1)/2; rp = rcp(ep.x*ep.y)
//   A(k)  : H_j(k-1) = pk_fma(ep, -G2*rp, G2)   (component-swapped tanh pair)
//           part(k-1) += C0d2*H_layer1 ; pass1: in_, w8(k), sg, rt chains.
// 3 trans + ~10 VALU per j-body, 8 independent bodies -> the in-order issue
// stream keeps the VALU fed while the quarter-rate trans pipe drains (the
// old breadth-first exp2/rcp blocks left the VALU idle ~200 cy/step).
//   r~-fold: FT_j == -1568*mE2_j exactly (rt seeded with -1568*du).
//   sigma-rescale: s = PiL*sg, w8 coeff mE2_j*Pi_{j-1} == K_j.
// Deferred-H also collapses the y0 pipeline to ONE reg with exact lag 2:
// y0cur = part(k-1) is set at step k and consumed as du at step k+1
// (layer2 stream at iteration k executes its step k-2).
// Init w8 = 0, S0 = 0 gives yy = 0 -> ep = 1, rp = 1 -> H(-1) = 0 exactly.
template<int PAR>
static __device__ __forceinline__ void fstep(
        v2 (&w8)[8], v2& S0, float& y0cur, float u,
        const float (&P2)[8], const float (&G2)[8], const float (&mE2)[8],
        const float (&K_)[8], const float (&Psp)[8],
        const float (&C0d2)[8], float PiL,
        const float (&ac)[6], const float (&bc)[6]) {
    v2 du;
    if (PAR) { du.x = y0cur; du.y = u; } else { du.x = u; du.y = y0cur; }
    v2 rt = sp(-1568.0f) * du;
    v2 sg = sp(0.f);
    float part = 0.f;
#pragma unroll
    for (int j = 0; j < 8; ++j) {
        // ---- B(k-1), index j: finish previous step's tanh inputs
        v2 yy = vfma(sp(K_[j]), S0, w8[j]);
        v2 E;
        E.x = __builtin_amdgcn_exp2f(yy.x);
        E.y = __builtin_amdgcn_exp2f(yy.y);
        v2 ep = vfma(E, sp(0.5f), sp(0.5f));       // (E+1)/2
        float rp = __builtin_amdgcn_rcpf(ep.x * ep.y);
        // ---- A(k), index j: materialize H_j(k-1), dot-partial, pass 1
        float nt = -G2[j] * rp;
        v2 Hj = vfma(ep, sp(nt), sp(G2[j]));       // swapped tanh pair * G2
        float hl1 = PAR ? Hj.y : Hj.x;             // layer-1 component
        part = fmaf(C0d2[j], hl1, part);
        v2 in_ = vfma(sp(mE2[j]), rt, Hj);
        w8[j] = (j == 0) ? in_ : vfma(sp(K_[j]), sg, in_);  // sg BEFORE update
        sg = (j == 0) ? sp(Psp[0]) * in_ : vfma(sp(Psp[j]), in_, sg);
        rt = vfma(sp(P2[j]), Hj, rt);
    }
    v2 r = vfma(sp(1568.0f), du, rt);              // recover true r
    v2 s = sp(PiL) * sg;                           // true local s for the scan

    // part-reduce (part = y0(k-1)): independent DPP chain, interleaves with
    // the scan below; consumed only at step k+1's du.
    part += dpp0<0x111, 0xF>(part);
    part += dpp0<0x112, 0xF>(part);
    part += dpp0<0x114, 0xF>(part);
    part += dpp0<0x118, 0xF>(part);
    part += dpp0<0x142, 0xA>(part);
    part += dpp0<0x143, 0xC>(part);

    LVL(0x111, 0xF, 0)   // row_shr:1
    LVL(0x112, 0xF, 1)   // row_shr:2
    LVL(0x114, 0xF, 2)   // row_shr:4
    LVL(0x118, 0xF, 3)   // row_shr:8
    LVL(0x142, 0xA, 4)   // row_bcast:15 -> rows 1,3
    LVL(0x143, 0xC, 5)   // row_bcast:31 -> rows 2,3

    v2 t = r + s;
    S0.x = dpp0<0x138, 0xF>(t.x);                  // exclusive: lane0 = 0
    S0.y = dpp0<0x138, 0xF>(t.y);
    y0cur = __builtin_bit_cast(float,
              __builtin_amdgcn_readlane(__builtin_bit_cast(int, part), 63));
}

// One wave per batch row; lane owns 8 hidden elems; layers 1/2 ride in .x/.y
// of packed fp32 (parity-alternating order), layer 2 lagging TWO steps.
// 98 phases x 8 steps (u batched as two ds_read_b128), then 2 pad steps
// (u = 0), then a tail-B materializing the final layer-2 state.
__global__ __launch_bounds__(256, 1) void ssm_main(const float* __restrict__ x,
                                                   const float* __restrict__ C0,
                                                   const float* __restrict__ Mmat,
                                                   const float* __restrict__ bias,
                                                   float* __restrict__ out) {
    const int tid = threadIdx.x;
    const int wave = tid >> 6;
    const int lane = tid & 63;
    const int row = blockIdx.x * 4 + wave;

    __shared__ __align__(16) float xs[4][SEQL + 8];   // row stride 792 (16B aligned)

    const float DEL = 1.0f / 784.0f;
    {
        const float4* __restrict__ xv =
            (const float4*)(x + (size_t)blockIdx.x * 4 * SEQL);
#pragma unroll
        for (int it = 0; it < 4; ++it) {
            int idx = tid + it * 256;                 // float4 index, need < 784
            if (idx < SEQL) {
                float4 v = xv[idx];
                int r = idx / (SEQL / 4);
                int c = (idx % (SEQL / 4)) * 4;
                float4 w;
                w.x = DEL * v.x; w.y = DEL * v.y;
                w.z = DEL * v.z; w.w = DEL * v.w;
                *(float4*)&xs[r][c] = w;
            }
        }
    }
    if (tid < 32) xs[tid >> 3][SEQL + (tid & 7)] = 0.f;
    __syncthreads();

    // ---- per-lane constants (fp64 -> fp32, matching reference f64 A_d/B_d)
    const double cd = 1.0 / 1568.0;            // step/2
    const double F = 2.0 * 1.4426950408889634; // 2*log2(e) fold for exp2
    float P2[8], G2[8], mE2[8], C0d2[8], K_[8], Psp[8], PiL;
    double apD = 0.0, bpD = 1.0;               // in-lane partial (alpha, beta)
    double Aprod = 1.0;                        // prod of a_m, m < j
#pragma unroll
    for (int j = 0; j < 8; ++j) {
        int i = lane * 8 + j;
        double Pd = sqrt(1.0 + 2.0 * (double)i);
        double dd = 1.0 + cd * (double)(i + 1);
        double fd = 1.0 / dd;
        double ad = (1.0 - cd * (double)i) * fd;
        double mEd = -cd * Pd * fd;
        double ed = Pd * mEd;                   // -cP^2/d ; note 1 - a + e == 0
        double Gd = (1.0 - cd * (double)(i + 1)) * fd;
        double G2d = F * Gd;
        apD = ad * apD + ed;
        bpD = ad * bpD;
        P2[j]  = (float)(Pd / G2d);             // r advances on H = G2*h
        G2[j]  = (float)G2d;
        mE2[j] = (float)(F * mEd);              // FT_j == -1568*mE2_j
        K_[j]  = (float)(F * mEd * Aprod);      // mE2_j * prod_{m<j} a_m
        Psp[j] = (float)((Pd / F) / (Aprod * ad)); // Ps_j / Pi_j
        Aprod *= ad;
        C0d2[j] = (float)((double)DEL * (double)C0[i] / G2d);
    }
    PiL = (float)Aprod;                         // Pi_7
    // ---- scan-level constants mirroring the DPP segment structure
    float ac[6], bc[6];
    {
        double al = apD, be = bpD;
        int rl = lane & 15;
#pragma unroll
        for (int L = 0; L < 4; ++L) {          // row_shr:1,2,4,8 (row-capped)
            int d = 1 << L;
            ac[L] = (float)al; bc[L] = (float)be;
            double pa = __shfl_up(al, d, 64);
            double pb = __shfl_up(be, d, 64);
            if (rl >= d) { al += be * pa; be *= pb; }
        }
        ac[4] = (float)al; bc[4] = (float)be;  // row_bcast:15 -> rows 1,3
        {
            int src = (lane & 32) + 15;
            double pa = __shfl(al, src, 64);
            double pb = __shfl(be, src, 64);
            if (lane & 16) { al += be * pa; be *= pb; }
        }
        ac[5] = (float)al; bc[5] = (float)be;  // row_bcast:31 -> rows 2,3
        {
            double pa = __shfl(al, 31, 64);
            double pb = __shfl(be, 31, 64);
            if (lane >= 32) { al += be * pa; be *= pb; }
        }
    }

    v2 w8[8], S0 = sp(0.f);
#pragma unroll
    for (int j = 0; j < 8; ++j) w8[j] = sp(0.f);
    float y0cur = 0.f;
    const float* xrow = xs[wave];

    for (int p = 0; p < 98; ++p) {
        const float4* up = (const float4*)&xrow[p * 8];
        float4 u0 = up[0], u1v = up[1];
        float ub[8] = {u0.x, u0.y, u0.z, u0.w, u1v.x, u1v.y, u1v.z, u1v.w};
#pragma unroll
        for (int q = 0; q < 4; ++q) {
            fstep<0>(w8, S0, y0cur, ub[2 * q],     P2, G2, mE2, K_, Psp,
                     C0d2, PiL, ac, bc);
            fstep<1>(w8, S0, y0cur, ub[2 * q + 1], P2, G2, mE2, K_, Psp,
                     C0d2, PiL, ac, bc);
        }
    }
    // pad steps k = 784 (even), 785 (odd): u = 0
    fstep<0>(w8, S0, y0cur, 0.f, P2, G2, mE2, K_, Psp, C0d2, PiL, ac, bc);
    fstep<1>(w8, S0, y0cur, 0.f, P2, G2, mE2, K_, Psp, C0d2, PiL, ac, bc);

    // ---- tail-B: materialize final layer-2 state from (S0, w8) of step 785.
    // A(785) was odd-parity: streams (.x = L2, .y = L1); the swapped tanh
    // pair puts layer-2 = 1 - rp*ep.y (unscaled; G2 cancels in the dot).
    float hv[8];
#pragma unroll
    for (int j = 0; j < 8; ++j) {
        v2 yy = vfma(sp(K_[j]), S0, w8[j]);
        v2 E;
        E.x = __builtin_amdgcn_exp2f(yy.x);
        E.y = __builtin_amdgcn_exp2f(yy.y);
        v2 ep = vfma(E, sp(0.5f), sp(0.5f));
        float rp = __builtin_amdgcn_rcpf(ep.x * ep.y);
        hv[j] = fmaf(-rp, ep.y, 1.0f);         // tanh of the .x (L2) stream
    }

    // ---- epilogue: logits[row] = h2_final @ M + b (M direct from global/L2)
    float acc[OUTD];
#pragma unroll
    for (int o = 0; o < OUTD; ++o) acc[o] = 0.f;
#pragma unroll
    for (int j = 0; j < 8; ++j) {
        int i = lane * 8 + j;
#pragma unroll
        for (int o = 0; o < OUTD; ++o)
            acc[o] = fmaf(hv[j], Mmat[i * OUTD + o], acc[o]);
    }
#pragma unroll
    for (int o = 0; o < OUTD; ++o) {
#pragma unroll
        for (int d = 32; d; d >>= 1) acc[o] += __shfl_xor(acc[o], d, 64);
    }
    if (lane == 0) {
#pragma unroll
        for (int o = 0; o < OUTD; ++o) out[row * OUTD + o] = acc[o] + bias[o];
    }
}

extern "C" void kernel_launch(void* const* d_in, const int* in_sizes, int n_in,
                              void* d_out, int out_size, void* d_ws, size_t ws_size,
                              hipStream_t stream) {
    const float* x  = (const float*)d_in[0];  // (1024, 784)
    const float* C0 = (const float*)d_in[1];  // (1, 512)
    const float* C1 = (const float*)d_in[2];  // (512, 512)
    const float* W  = (const float*)d_in[3];  // (512, 10)
    const float* b  = (const float*)d_in[4];  // (10,)
    float* M = (float*)d_ws;                  // 512*10 fp32 scratch

    compute_M<<<dim3(8), dim3(256), 0, stream>>>(C1, W, M);
    ssm_main<<<dim3(256), dim3(256), 0, stream>>>(x, C0, M, b, (float*)d_out);
}